// Round 14
// baseline (269.427 us; speedup 1.0000x reference)
//
#include <hip/hip_runtime.h>
#include <hip/hip_bf16.h>
#include <stdint.h>

typedef __bf16 bf16;
typedef __bf16 bf16x8 __attribute__((ext_vector_type(8)));
typedef __bf16 bf16x4 __attribute__((ext_vector_type(4)));
typedef float f32x4 __attribute__((ext_vector_type(4)));
typedef float f32x16 __attribute__((ext_vector_type(16)));

#define NB 4
#define SEQ 2048
#define DM 1024
#define NHEADS 16
#define DHEAD 64
#define MTOK (NB*SEQ)      /* 8192 */
#define NE 3072            /* 3*DM */

__device__ __forceinline__ void gl_lds16(const bf16* g, bf16* l) {
  __builtin_amdgcn_global_load_lds(
      (const __attribute__((address_space(1))) void*)g,
      (__attribute__((address_space(3))) void*)l, 16, 0, 0);
}

__device__ __forceinline__ f32x16 zero16() {
  f32x16 z;
#pragma unroll
  for (int i=0;i<16;i++) z[i]=0.f;
  return z;
}

// ---------------- convert inputs to bf16 ----------------
__global__ __launch_bounds__(256) void convert_kernel(
    const float* __restrict__ x,
    const float* __restrict__ wq, const float* __restrict__ wk,
    const float* __restrict__ wv, const float* __restrict__ wo,
    const float* __restrict__ bq, const float* __restrict__ bk,
    const float* __restrict__ bv,
    bf16* __restrict__ xb, bf16* __restrict__ wqkvb,
    bf16* __restrict__ wob, float* __restrict__ bqkv) {
  int tid = blockIdx.x*blockDim.x + threadIdx.x;
  int nt = gridDim.x*blockDim.x;
  const int NX4 = MTOK*DM/4;
  for (int i = tid; i < NX4; i += nt) {
    float4 v = ((const float4*)x)[i];
    ((bf16x4*)xb)[i] = bf16x4{(bf16)v.x,(bf16)v.y,(bf16)v.z,(bf16)v.w};
  }
  const int NW4 = DM*DM/4;
  for (int i = tid; i < NW4; i += nt) {
    float4 a = ((const float4*)wq)[i];
    ((bf16x4*)wqkvb)[i] = bf16x4{(bf16)a.x,(bf16)a.y,(bf16)a.z,(bf16)a.w};
    float4 b = ((const float4*)wk)[i];
    ((bf16x4*)wqkvb)[i+NW4] = bf16x4{(bf16)b.x,(bf16)b.y,(bf16)b.z,(bf16)b.w};
    float4 c = ((const float4*)wv)[i];
    ((bf16x4*)wqkvb)[i+2*NW4] = bf16x4{(bf16)c.x,(bf16)c.y,(bf16)c.z,(bf16)c.w};
    float4 d = ((const float4*)wo)[i];
    ((bf16x4*)wob)[i] = bf16x4{(bf16)d.x,(bf16)d.y,(bf16)d.z,(bf16)d.w};
  }
  for (int i = tid; i < DM; i += nt) {
    bqkv[i] = bq[i]; bqkv[i+DM] = bk[i]; bqkv[i+2*DM] = bv[i];
  }
}

// ---- GEMM: 128x128, BK=64, dbuf LDS, counted vmcnt(8), XOR-swizzled (R7 exact) ----
template<int OUT_MODE>
__global__ __launch_bounds__(256) void gemm_deep(
    const bf16* __restrict__ A, const bf16* __restrict__ Bm,
    const float* __restrict__ bias, void* __restrict__ Cout,
    int M, int N, int K) {
  __shared__ bf16 As[2][128*64];
  __shared__ bf16 Bs[2][128*64];
  const int bm = blockIdx.x, bn = blockIdx.y;
  const int thr = threadIdx.x;
  const int w = thr>>6, lane = thr&63;
  const int wr = w>>1, wc = w&1;
  const int l4 = lane>>4, lm = lane&15;
  f32x4 acc[4][4];
#pragma unroll
  for (int m=0;m<4;m++)
#pragma unroll
    for (int n=0;n<4;n++) acc[m][n] = f32x4{0.f,0.f,0.f,0.f};

  const bf16* Abase = A + (size_t)bm*128*K;
  const bf16* Bbase = Bm + (size_t)bn*128*K;

  const int srow = thr>>3;
  const int sch  = ((thr&7) ^ (srow&7)) * 8;
  const bf16* Ag = Abase + (size_t)srow*K + sch;
  const bf16* Bg = Bbase + (size_t)srow*K + sch;
  const int dbase = thr*8;

  const int nk = K>>6;

  int aoff[2][4], boff[2][4];
#pragma unroll
  for (int ks=0;ks<2;ks++) {
#pragma unroll
    for (int m=0;m<4;m++) {
      const int r = wr*64 + m*16 + lm;
      aoff[ks][m] = r*64 + ((((ks<<2)|l4) ^ (lm&7))*8);
    }
#pragma unroll
    for (int n=0;n<4;n++) {
      const int r = wc*64 + n*16 + lm;
      boff[ks][n] = r*64 + ((((ks<<2)|l4) ^ (lm&7))*8);
    }
  }

#pragma unroll
  for (int c=0;c<4;c++) {
    gl_lds16(Ag + (size_t)c*32*K, &As[0][c*2048 + dbase]);
    gl_lds16(Bg + (size_t)c*32*K, &Bs[0][c*2048 + dbase]);
  }

  for (int kt=0; kt<nk; ++kt) {
    const int p = kt&1;
    const int st = (kt+1 < nk) ? kt+1 : 0;
    const size_t ko = (size_t)st*64;
#pragma unroll
    for (int c=0;c<4;c++) {
      gl_lds16(Ag + ko + (size_t)c*32*K, &As[p^1][c*2048 + dbase]);
      gl_lds16(Bg + ko + (size_t)c*32*K, &Bs[p^1][c*2048 + dbase]);
    }
    asm volatile("s_waitcnt vmcnt(8)" ::: "memory");
    __builtin_amdgcn_s_barrier();
    __builtin_amdgcn_sched_barrier(0);

    const bf16* Ac = As[p];
    const bf16* Bc = Bs[p];
    __builtin_amdgcn_s_setprio(1);
#pragma unroll
    for (int ks=0;ks<2;ks++) {
      bf16x8 af[4], bfr[4];
#pragma unroll
      for (int m=0;m<4;m++) af[m] = *(const bf16x8*)&Ac[aoff[ks][m]];
#pragma unroll
      for (int n=0;n<4;n++) bfr[n] = *(const bf16x8*)&Bc[boff[ks][n]];
#pragma unroll
      for (int m=0;m<4;m++)
#pragma unroll
        for (int n=0;n<4;n++)
          acc[m][n] = __builtin_amdgcn_mfma_f32_16x16x32_bf16(af[m], bfr[n], acc[m][n], 0, 0, 0);
    }
    __builtin_amdgcn_s_setprio(0);
    __builtin_amdgcn_s_barrier();
    __builtin_amdgcn_sched_barrier(0);
  }

  const int rbase = bm*128 + wr*64 + l4*4;
  const int cbase = bn*128 + wc*64;
#pragma unroll
  for (int n=0;n<4;n++) {
    const int col = cbase + n*16 + lm;
    const float bv = bias[col];
#pragma unroll
    for (int m=0;m<4;m++) {
#pragma unroll
      for (int j=0;j<4;j++) {
        const int row = rbase + m*16 + j;
        const float v = acc[m][n][j] + bv;
        if (OUT_MODE == 0) ((bf16*)Cout)[(size_t)row*N + col] = (bf16)v;
        else               ((float*)Cout)[(size_t)row*N + col] = v;
      }
    }
  }
}

// ---------------- transpose V: qkv[b,s, 2048+h*64+d] -> vt[b,h,d,s] ----------------
__global__ __launch_bounds__(256) void transpose_v(const bf16* __restrict__ qkv,
                                                   bf16* __restrict__ vt) {
  __shared__ bf16 tile[64*72];
  const int s0 = blockIdx.x*64;
  const int bh = blockIdx.y;
  const bf16* src = qkv + (size_t)((bh>>4)*SEQ + s0)*NE + 2*DM + (bh&15)*64;
  const int thr = threadIdx.x;
#pragma unroll
  for (int i=0;i<2;i++) {
    int idx = thr + i*256;
    int row = idx>>3, part = idx&7;
    *(bf16x8*)&tile[row*72 + part*8] = *(const bf16x8*)(src + (size_t)row*NE + part*8);
  }
  __syncthreads();
  bf16* dst = vt + (size_t)bh*64*SEQ + s0;
#pragma unroll
  for (int i=0;i<2;i++) {
    int idx = thr + i*256;
    int d = idx>>3, part = idx&7;
    bf16x8 v;
#pragma unroll
    for (int j=0;j<8;j++) v[j] = tile[(part*8+j)*72 + d];
    *(bf16x8*)(dst + (size_t)d*SEQ + part*8) = v;
  }
}

// ---------------- flash attention: barrier-free KV-split ----------------
// grid: 1024 blocks (XCD-swizzled: 8 bh per XCD -> KV L2-local), block 256.
// Block covers 128 q-rows; 4 waves = 2 q-groups x 2 kv-halves. Each wave reads
// its K/V fragments directly from L2 (per-lane global_load_dwordx4, 1-tile reg
// prefetch), NO barriers / NO LDS in the main loop. Fixed-max softmax makes the
// kv-split combine pure addition (o,l partials) -> 2-barrier LDS combine at end.
__global__ __launch_bounds__(256, 2) void attn_kernel(
    const bf16* __restrict__ qkv, const bf16* __restrict__ vt,
    bf16* __restrict__ aout,
    const float* __restrict__ temperature, const float* __restrict__ q_scale) {
  __shared__ float cmb[2][64][96];   // combine buffer (used only at tail)
  const int bid = blockIdx.x;                 // 0..1023
  const int swz = (bid & 7)*128 + (bid >> 3); // bijective XCD chunking
  const int bh = swz >> 4;                    // 0..63  (8 bh per XCD)
  const int qb = swz & 15;                    // 0..15
  const int b = bh >> 4, h = bh & 15;
  const int thr = threadIdx.x;
  const int w = thr >> 6, lane = thr & 63;
  const int qg = w >> 1, kh = w & 1;          // q-group, kv-half
  const int l31 = lane & 31, hi = lane >> 5;
  const float sc2 = 1.4426950408889634f / (8.0f * temperature[0]);
  const int q0 = qb*128 + qg*64;
  const int NTW = SEQ/64/2;                   // 16 tiles per wave

  // Q fragments for both q-halves, pre-scaled by sc2
  bf16x8 qfA[4], qfB[4];
  {
    const bf16* qpA = qkv + (size_t)(b*SEQ + q0 + l31)*NE + h*64 + hi*8;
    const bf16* qpB = qpA + (size_t)32*NE;
#pragma unroll
    for (int s=0;s<4;s++) {
      bf16x8 qa = *(const bf16x8*)(qpA + s*16);
      bf16x8 qb_ = *(const bf16x8*)(qpB + s*16);
#pragma unroll
      for (int j=0;j<8;j++) {
        qfA[s][j] = (bf16)((float)qa[j] * sc2);
        qfB[s][j] = (bf16)((float)qb_[j] * sc2);
      }
    }
  }

  f32x16 oA0 = zero16(), oA1 = zero16(), lA = zero16();
  f32x16 oB0 = zero16(), oB1 = zero16(), lB = zero16();
  const bf16 onev = (bf16)1.0f;
  const bf16x8 ones = {onev,onev,onev,onev,onev,onev,onev,onev};

  // per-lane fragment base pointers
  // K frag (t, s, half): row = kh*1024 + t*64 + half*32 + l31, d-off = s*16 + hi*8
  const bf16* kp0 = qkv + (size_t)b*SEQ*NE + DM + h*64
                  + (size_t)(kh*1024 + l31)*NE + hi*8;          // half 0
  const bf16* kp1 = kp0 + (size_t)32*NE;                        // half 1
  // V frag (t, s, half): row d = half*32 + l31, k-off = kh*1024 + t*64 + s*16 + hi*8
  const bf16* vp0 = vt + (size_t)bh*64*SEQ + (size_t)l31*SEQ + kh*1024 + hi*8;
  const bf16* vp1 = vp0 + (size_t)32*SEQ;

  // prologue: load K frags for tile 0
  bf16x8 kf0[4], kf1[4];
#pragma unroll
  for (int s=0;s<4;s++) {
    kf0[s] = *(const bf16x8*)(kp0 + s*16);
    kf1[s] = *(const bf16x8*)(kp1 + s*16);
  }

  for (int t=0; t<NTW; ++t) {
    const int koff = t*64;
    // issue V loads for current tile (consumed after QK+exp)
    bf16x8 vf0[4], vf1[4];
#pragma unroll
    for (int s=0;s<4;s++) {
      vf0[s] = *(const bf16x8*)(vp0 + koff + s*16);
      vf1[s] = *(const bf16x8*)(vp1 + koff + s*16);
    }

    // QK^T: St[k][q] = K Q
    f32x16 sA0 = zero16(), sA1 = zero16(), sB0 = zero16(), sB1 = zero16();
    __builtin_amdgcn_s_setprio(1);
#pragma unroll
    for (int s=0;s<4;s++) {
      sA0 = __builtin_amdgcn_mfma_f32_32x32x16_bf16(kf0[s], qfA[s], sA0, 0,0,0);
      sB0 = __builtin_amdgcn_mfma_f32_32x32x16_bf16(kf0[s], qfB[s], sB0, 0,0,0);
      sA1 = __builtin_amdgcn_mfma_f32_32x32x16_bf16(kf1[s], qfA[s], sA1, 0,0,0);
      sB1 = __builtin_amdgcn_mfma_f32_32x32x16_bf16(kf1[s], qfB[s], sB1, 0,0,0);
    }
    __builtin_amdgcn_s_setprio(0);

    // prefetch K frags for next tile (dummy re-read of last tile on t=NTW-1)
    {
      const int kn = (t+1 < NTW) ? (t+1)*64 : koff;
#pragma unroll
      for (int s=0;s<4;s++) {
        kf0[s] = *(const bf16x8*)(kp0 + (size_t)kn*NE + s*16);
        kf1[s] = *(const bf16x8*)(kp1 + (size_t)kn*NE + s*16);
      }
    }

    // softmax, fixed max = 0 (scale folded into Q)
#pragma unroll
    for (int r=0;r<16;r++) sA0[r] = __builtin_amdgcn_exp2f(sA0[r]);
#pragma unroll
    for (int r=0;r<16;r++) sA1[r] = __builtin_amdgcn_exp2f(sA1[r]);
#pragma unroll
    for (int r=0;r<16;r++) sB0[r] = __builtin_amdgcn_exp2f(sB0[r]);
#pragma unroll
    for (int r=0;r<16;r++) sB1[r] = __builtin_amdgcn_exp2f(sB1[r]);

    // PV + rowsum via ones-MFMA
    __builtin_amdgcn_s_setprio(1);
#pragma unroll
    for (int ks=0;ks<4;ks++) {
      float e0,e1,e2,e3,e4,e5,e6,e7;
      float f0,f1,f2,f3,f4,f5,f6,f7;
      if (ks==0)      { e0=sA0[0]; e1=sA0[1]; e2=sA0[2]; e3=sA0[3]; e4=sA0[4]; e5=sA0[5]; e6=sA0[6]; e7=sA0[7];
                        f0=sB0[0]; f1=sB0[1]; f2=sB0[2]; f3=sB0[3]; f4=sB0[4]; f5=sB0[5]; f6=sB0[6]; f7=sB0[7]; }
      else if (ks==1) { e0=sA0[8]; e1=sA0[9]; e2=sA0[10];e3=sA0[11];e4=sA0[12];e5=sA0[13];e6=sA0[14];e7=sA0[15];
                        f0=sB0[8]; f1=sB0[9]; f2=sB0[10];f3=sB0[11];f4=sB0[12];f5=sB0[13];f6=sB0[14];f7=sB0[15]; }
      else if (ks==2) { e0=sA1[0]; e1=sA1[1]; e2=sA1[2]; e3=sA1[3]; e4=sA1[4]; e5=sA1[5]; e6=sA1[6]; e7=sA1[7];
                        f0=sB1[0]; f1=sB1[1]; f2=sB1[2]; f3=sB1[3]; f4=sB1[4]; f5=sB1[5]; f6=sB1[6]; f7=sB1[7]; }
      else            { e0=sA1[8]; e1=sA1[9]; e2=sA1[10];e3=sA1[11];e4=sA1[12];e5=sA1[13];e6=sA1[14];e7=sA1[15];
                        f0=sB1[8]; f1=sB1[9]; f2=sB1[10];f3=sB1[11];f4=sB1[12];f5=sB1[13];f6=sB1[14];f7=sB1[15]; }
      unsigned a0,a1,b0,b1,c0,c1,d0,d1;
      asm("v_cvt_pk_bf16_f32 %0, %1, %2" : "=v"(a0) : "v"(e0), "v"(e1));
      asm("v_cvt_pk_bf16_f32 %0, %1, %2" : "=v"(a1) : "v"(e2), "v"(e3));
      asm("v_cvt_pk_bf16_f32 %0, %1, %2" : "=v"(b0) : "v"(e4), "v"(e5));
      asm("v_cvt_pk_bf16_f32 %0, %1, %2" : "=v"(b1) : "v"(e6), "v"(e7));
      asm("v_permlane32_swap_b32 %0, %1" : "+v"(a0), "+v"(b0));
      asm("v_permlane32_swap_b32 %0, %1" : "+v"(a1), "+v"(b1));
      asm("v_cvt_pk_bf16_f32 %0, %1, %2" : "=v"(c0) : "v"(f0), "v"(f1));
      asm("v_cvt_pk_bf16_f32 %0, %1, %2" : "=v"(c1) : "v"(f2), "v"(f3));
      asm("v_cvt_pk_bf16_f32 %0, %1, %2" : "=v"(d0) : "v"(f4), "v"(f5));
      asm("v_cvt_pk_bf16_f32 %0, %1, %2" : "=v"(d1) : "v"(f6), "v"(f7));
      asm("v_permlane32_swap_b32 %0, %1" : "+v"(c0), "+v"(d0));
      asm("v_permlane32_swap_b32 %0, %1" : "+v"(c1), "+v"(d1));
      union { unsigned u[4]; bf16x8 v; } puA, puB;
      puA.u[0]=a0; puA.u[1]=a1; puA.u[2]=b0; puA.u[3]=b1;
      puB.u[0]=c0; puB.u[1]=c1; puB.u[2]=d0; puB.u[3]=d1;
      oA0 = __builtin_amdgcn_mfma_f32_32x32x16_bf16(puA.v, vf0[ks], oA0, 0,0,0);
      oA1 = __builtin_amdgcn_mfma_f32_32x32x16_bf16(puA.v, vf1[ks], oA1, 0,0,0);
      lA  = __builtin_amdgcn_mfma_f32_32x32x16_bf16(puA.v, ones, lA, 0,0,0);
      oB0 = __builtin_amdgcn_mfma_f32_32x32x16_bf16(puB.v, vf0[ks], oB0, 0,0,0);
      oB1 = __builtin_amdgcn_mfma_f32_32x32x16_bf16(puB.v, vf1[ks], oB1, 0,0,0);
      lB  = __builtin_amdgcn_mfma_f32_32x32x16_bf16(puB.v, ones, lB, 0,0,0);
    }
    __builtin_amdgcn_s_setprio(0);
  }

  // ---- combine kv-halves (partials add exactly: fixed max) ----
  __syncthreads();
  if (kh == 1) {
    float* dst = &cmb[qg][lane][0];
#pragma unroll
    for (int r=0;r<16;r++) {
      dst[r]      = oA0[r];
      dst[16+r]   = oA1[r];
      dst[32+r]   = oB0[r];
      dst[48+r]   = oB1[r];
      dst[64+r]   = lA[r];
      dst[80+r]   = lB[r];
    }
  }
  __syncthreads();
  if (kh == 0) {
    const float* src = &cmb[qg][lane][0];
#pragma unroll
    for (int r=0;r<16;r++) {
      oA0[r] += src[r];
      oA1[r] += src[16+r];
      oB0[r] += src[32+r];
      oB1[r] += src[48+r];
      lA[r]  += src[64+r];
      lB[r]  += src[80+r];
    }
    const float qs = q_scale[h];
#pragma unroll
    for (int r=0;r<16;r++) {
      const int qi = (r&3) + 8*(r>>2) + hi*4;
      {
        const float iv = qs / lA[r];
        bf16* op = aout + (size_t)(b*SEQ + q0 + qi)*DM + h*64 + l31;
        op[0]  = (bf16)(oA0[r]*iv);
        op[32] = (bf16)(oA1[r]*iv);
      }
      {
        const float iv = qs / lB[r];
        bf16* op = aout + (size_t)(b*SEQ + q0 + 32 + qi)*DM + h*64 + l31;
        op[0]  = (bf16)(oB0[r]*iv);
        op[32] = (bf16)(oB1[r]*iv);
      }
    }
  }
}

// ---------------- launch ----------------
extern "C" void kernel_launch(void* const* d_in, const int* in_sizes, int n_in,
                              void* d_out, int out_size, void* d_ws, size_t ws_size,
                              hipStream_t stream) {
  (void)in_sizes; (void)n_in; (void)out_size; (void)ws_size;
  const float* x  = (const float*)d_in[0];
  const float* wq = (const float*)d_in[1];
  const float* bq = (const float*)d_in[2];
  const float* wk = (const float*)d_in[3];
  const float* bk = (const float*)d_in[4];
  const float* wv = (const float*)d_in[5];
  const float* bv = (const float*)d_in[6];
  const float* wo = (const float*)d_in[7];
  const float* bo = (const float*)d_in[8];
  const float* temp = (const float*)d_in[9];
  const float* qsc  = (const float*)d_in[10];

  char* ws = (char*)d_ws;
  bf16* xb    = (bf16*)ws; ws += (size_t)MTOK*DM*2;
  bf16* wqkvb = (bf16*)ws; ws += (size_t)NE*DM*2;
  bf16* wob   = (bf16*)ws; ws += (size_t)DM*DM*2;
  float* bqkv = (float*)ws; ws += (size_t)NE*4;
  bf16* qkv   = (bf16*)ws; ws += (size_t)MTOK*NE*2;
  bf16* vt    = (bf16*)ws; ws += (size_t)NB*NHEADS*DHEAD*SEQ*2;
  bf16* aout  = (bf16*)ws; ws += (size_t)MTOK*DM*2;

  convert_kernel<<<dim3(1024), dim3(256), 0, stream>>>(x, wq, wk, wv, wo, bq, bk, bv,
                                                       xb, wqkvb, wob, bqkv);
  gemm_deep<0><<<dim3(MTOK/128, NE/128), dim3(256), 0, stream>>>(xb, wqkvb, bqkv, qkv,
                                                                 MTOK, NE, DM);
  transpose_v<<<dim3(SEQ/64, NB*NHEADS), dim3(256), 0, stream>>>(qkv, vt);
  attn_kernel<<<dim3(1024), dim3(256), 0, stream>>>(qkv, vt, aout, temp, qsc);
  gemm_deep<1><<<dim3(MTOK/128, DM/128), dim3(256), 0, stream>>>(aout, wob, bo, d_out,
                                                                 MTOK, DM, DM);
}

// Round 15
// 179.615 us; speedup vs baseline: 1.5000x; 1.5000x over previous
//
#include <hip/hip_runtime.h>
#include <hip/hip_bf16.h>
#include <stdint.h>

typedef __bf16 bf16;
typedef __bf16 bf16x8 __attribute__((ext_vector_type(8)));
typedef __bf16 bf16x4 __attribute__((ext_vector_type(4)));
typedef float f32x4 __attribute__((ext_vector_type(4)));
typedef float f32x16 __attribute__((ext_vector_type(16)));

#define NB 4
#define SEQ 2048
#define DM 1024
#define NHEADS 16
#define DHEAD 64
#define MTOK (NB*SEQ)      /* 8192 */
#define NE 3072            /* 3*DM */

__device__ __forceinline__ void gl_lds16(const bf16* g, bf16* l) {
  __builtin_amdgcn_global_load_lds(
      (const __attribute__((address_space(1))) void*)g,
      (__attribute__((address_space(3))) void*)l, 16, 0, 0);
}

__device__ __forceinline__ f32x16 zero16() {
  f32x16 z;
#pragma unroll
  for (int i=0;i<16;i++) z[i]=0.f;
  return z;
}

// ---------------- convert inputs to bf16 ----------------
__global__ __launch_bounds__(256) void convert_kernel(
    const float* __restrict__ x,
    const float* __restrict__ wq, const float* __restrict__ wk,
    const float* __restrict__ wv, const float* __restrict__ wo,
    const float* __restrict__ bq, const float* __restrict__ bk,
    const float* __restrict__ bv,
    bf16* __restrict__ xb, bf16* __restrict__ wqkvb,
    bf16* __restrict__ wob, float* __restrict__ bqkv) {
  int tid = blockIdx.x*blockDim.x + threadIdx.x;
  int nt = gridDim.x*blockDim.x;
  const int NX4 = MTOK*DM/4;
  for (int i = tid; i < NX4; i += nt) {
    float4 v = ((const float4*)x)[i];
    ((bf16x4*)xb)[i] = bf16x4{(bf16)v.x,(bf16)v.y,(bf16)v.z,(bf16)v.w};
  }
  const int NW4 = DM*DM/4;
  for (int i = tid; i < NW4; i += nt) {
    float4 a = ((const float4*)wq)[i];
    ((bf16x4*)wqkvb)[i] = bf16x4{(bf16)a.x,(bf16)a.y,(bf16)a.z,(bf16)a.w};
    float4 b = ((const float4*)wk)[i];
    ((bf16x4*)wqkvb)[i+NW4] = bf16x4{(bf16)b.x,(bf16)b.y,(bf16)b.z,(bf16)b.w};
    float4 c = ((const float4*)wv)[i];
    ((bf16x4*)wqkvb)[i+2*NW4] = bf16x4{(bf16)c.x,(bf16)c.y,(bf16)c.z,(bf16)c.w};
    float4 d = ((const float4*)wo)[i];
    ((bf16x4*)wob)[i] = bf16x4{(bf16)d.x,(bf16)d.y,(bf16)d.z,(bf16)d.w};
  }
  for (int i = tid; i < DM; i += nt) {
    bqkv[i] = bq[i]; bqkv[i+DM] = bk[i]; bqkv[i+2*DM] = bv[i];
  }
}

// ---- GEMM: 128x128, BK=64, dbuf LDS, counted vmcnt(8), XOR-swizzled (R7 exact) ----
template<int OUT_MODE>
__global__ __launch_bounds__(256) void gemm_deep(
    const bf16* __restrict__ A, const bf16* __restrict__ Bm,
    const float* __restrict__ bias, void* __restrict__ Cout,
    int M, int N, int K) {
  __shared__ bf16 As[2][128*64];
  __shared__ bf16 Bs[2][128*64];
  const int bm = blockIdx.x, bn = blockIdx.y;
  const int thr = threadIdx.x;
  const int w = thr>>6, lane = thr&63;
  const int wr = w>>1, wc = w&1;
  const int l4 = lane>>4, lm = lane&15;
  f32x4 acc[4][4];
#pragma unroll
  for (int m=0;m<4;m++)
#pragma unroll
    for (int n=0;n<4;n++) acc[m][n] = f32x4{0.f,0.f,0.f,0.f};

  const bf16* Abase = A + (size_t)bm*128*K;
  const bf16* Bbase = Bm + (size_t)bn*128*K;

  const int srow = thr>>3;
  const int sch  = ((thr&7) ^ (srow&7)) * 8;
  const bf16* Ag = Abase + (size_t)srow*K + sch;
  const bf16* Bg = Bbase + (size_t)srow*K + sch;
  const int dbase = thr*8;

  const int nk = K>>6;

  int aoff[2][4], boff[2][4];
#pragma unroll
  for (int ks=0;ks<2;ks++) {
#pragma unroll
    for (int m=0;m<4;m++) {
      const int r = wr*64 + m*16 + lm;
      aoff[ks][m] = r*64 + ((((ks<<2)|l4) ^ (lm&7))*8);
    }
#pragma unroll
    for (int n=0;n<4;n++) {
      const int r = wc*64 + n*16 + lm;
      boff[ks][n] = r*64 + ((((ks<<2)|l4) ^ (lm&7))*8);
    }
  }

#pragma unroll
  for (int c=0;c<4;c++) {
    gl_lds16(Ag + (size_t)c*32*K, &As[0][c*2048 + dbase]);
    gl_lds16(Bg + (size_t)c*32*K, &Bs[0][c*2048 + dbase]);
  }

  for (int kt=0; kt<nk; ++kt) {
    const int p = kt&1;
    const int st = (kt+1 < nk) ? kt+1 : 0;
    const size_t ko = (size_t)st*64;
#pragma unroll
    for (int c=0;c<4;c++) {
      gl_lds16(Ag + ko + (size_t)c*32*K, &As[p^1][c*2048 + dbase]);
      gl_lds16(Bg + ko + (size_t)c*32*K, &Bs[p^1][c*2048 + dbase]);
    }
    asm volatile("s_waitcnt vmcnt(8)" ::: "memory");
    __builtin_amdgcn_s_barrier();
    __builtin_amdgcn_sched_barrier(0);

    const bf16* Ac = As[p];
    const bf16* Bc = Bs[p];
    __builtin_amdgcn_s_setprio(1);
#pragma unroll
    for (int ks=0;ks<2;ks++) {
      bf16x8 af[4], bfr[4];
#pragma unroll
      for (int m=0;m<4;m++) af[m] = *(const bf16x8*)&Ac[aoff[ks][m]];
#pragma unroll
      for (int n=0;n<4;n++) bfr[n] = *(const bf16x8*)&Bc[boff[ks][n]];
#pragma unroll
      for (int m=0;m<4;m++)
#pragma unroll
        for (int n=0;n<4;n++)
          acc[m][n] = __builtin_amdgcn_mfma_f32_16x16x32_bf16(af[m], bfr[n], acc[m][n], 0, 0, 0);
    }
    __builtin_amdgcn_s_setprio(0);
    __builtin_amdgcn_s_barrier();
    __builtin_amdgcn_sched_barrier(0);
  }

  const int rbase = bm*128 + wr*64 + l4*4;
  const int cbase = bn*128 + wc*64;
#pragma unroll
  for (int n=0;n<4;n++) {
    const int col = cbase + n*16 + lm;
    const float bv = bias[col];
#pragma unroll
    for (int m=0;m<4;m++) {
#pragma unroll
      for (int j=0;j<4;j++) {
        const int row = rbase + m*16 + j;
        const float v = acc[m][n][j] + bv;
        if (OUT_MODE == 0) ((bf16*)Cout)[(size_t)row*N + col] = (bf16)v;
        else               ((float*)Cout)[(size_t)row*N + col] = v;
      }
    }
  }
}

// ---------------- transpose V: qkv[b,s, 2048+h*64+d] -> vt[b,h,d,s] ----------------
__global__ __launch_bounds__(256) void transpose_v(const bf16* __restrict__ qkv,
                                                   bf16* __restrict__ vt) {
  __shared__ bf16 tile[64*72];
  const int s0 = blockIdx.x*64;
  const int bh = blockIdx.y;
  const bf16* src = qkv + (size_t)((bh>>4)*SEQ + s0)*NE + 2*DM + (bh&15)*64;
  const int thr = threadIdx.x;
#pragma unroll
  for (int i=0;i<2;i++) {
    int idx = thr + i*256;
    int row = idx>>3, part = idx&7;
    *(bf16x8*)&tile[row*72 + part*8] = *(const bf16x8*)(src + (size_t)row*NE + part*8);
  }
  __syncthreads();
  bf16* dst = vt + (size_t)bh*64*SEQ + s0;
#pragma unroll
  for (int i=0;i<2;i++) {
    int idx = thr + i*256;
    int d = idx>>3, part = idx&7;
    bf16x8 v;
#pragma unroll
    for (int j=0;j<8;j++) v[j] = tile[(part*8+j)*72 + d];
    *(bf16x8*)(dst + (size_t)d*SEQ + part*8) = v;
  }
}

// ---------------- flash attention: 4 waves x 64 q-rows (2 q-halves/wave) ----
// grid: (SEQ/256, NB*NHEADS), block 256, 2 blocks/CU.  R13 structure; rowsum moved
// off the matrix pipe: l accumulated as lane-local f32 adds in the exp loops
// (lane&31 == q for the St layout), cross-half shfl + q-redistribution deferred
// to the epilogue. Removes 8 of 40 MFMAs/tile and 30 VGPR.
__global__ __launch_bounds__(256, 2) void attn_kernel(
    const bf16* __restrict__ qkv, const bf16* __restrict__ vt,
    bf16* __restrict__ aout,
    const float* __restrict__ temperature, const float* __restrict__ q_scale) {
  __shared__ bf16 smem[4][64*64];   // [K0][K1][V0][V1], rows 128B, XOR-swizzled 16B chunks
  const int bh = blockIdx.y;
  const int b = bh>>4, h = bh&15;
  const int thr = threadIdx.x;
  const int w = thr>>6, lane = thr&63;
  const int l31 = lane&31, hi = lane>>5;
  const float sc2 = 1.4426950408889634f / (8.0f * temperature[0]);
  const int q0 = blockIdx.x*256 + w*64;
  const int NT = SEQ/64;
#define KBUFB 8192        /* bytes per buffer */
#define VOFFB 16384       /* V region byte offset */

  // Q fragments for both q-halves, pre-scaled by sc2
  bf16x8 qfA[4], qfB[4];
  {
    const bf16* qpA = qkv + (size_t)(b*SEQ + q0 + l31)*NE + h*64 + hi*8;
    const bf16* qpB = qpA + (size_t)32*NE;
#pragma unroll
    for (int s=0;s<4;s++) {
      bf16x8 qa = *(const bf16x8*)(qpA + s*16);
      bf16x8 qb = *(const bf16x8*)(qpB + s*16);
#pragma unroll
      for (int j=0;j<8;j++) {
        qfA[s][j] = (bf16)((float)qa[j] * sc2);
        qfB[s][j] = (bf16)((float)qb[j] * sc2);
      }
    }
  }

  f32x16 oA0 = zero16(), oA1 = zero16();
  f32x16 oB0 = zero16(), oB1 = zero16();
  float lpA = 0.f, lpB = 0.f;     // lane-local rowsum for q = lane&31 (this hi-half's k)

  const bf16* Kbase = qkv + (size_t)b*SEQ*NE + DM + h*64;
  const bf16* Vbase = vt + (size_t)bh*64*SEQ;

  // staging: thread -> row sr (0..63), chunk scb (0..3); swizzle chunk^=(row&7)
  const int sr = thr>>2, scb = thr&3;
  const int wb0 = sr*128 + (((scb*2+0) ^ (sr&7))<<4);
  const int wb1 = sr*128 + (((scb*2+1) ^ (sr&7))<<4);
  const int rsw = l31&7;

  // precomputed fragment read addresses; buffer/V region via imm offsets
  const char* kr0[4];
  const char* kr1[4];
#pragma unroll
  for (int s=0;s<4;s++) {
    const int slot = s*2 + hi;
    kr0[s] = (const char*)smem + l31*128      + ((slot ^ rsw)<<4);
    kr1[s] = (const char*)smem + (32+l31)*128 + ((slot ^ rsw)<<4);
  }

  const bf16* kgb = Kbase + (size_t)sr*NE + scb*16;
  const bf16* vgb = Vbase + (size_t)sr*SEQ + scb*16;

  bf16x8 ka, kb, va, vb;
  ka = *(const bf16x8*)(kgb);
  kb = *(const bf16x8*)(kgb + 8);
  va = *(const bf16x8*)(vgb);
  vb = *(const bf16x8*)(vgb + 8);
  *(bf16x8*)((char*)smem + wb0)         = ka;
  *(bf16x8*)((char*)smem + wb1)         = kb;
  *(bf16x8*)((char*)smem + VOFFB + wb0) = va;
  *(bf16x8*)((char*)smem + VOFFB + wb1) = vb;
  kgb += (size_t)64*NE; vgb += 64;
  ka = *(const bf16x8*)(kgb);
  kb = *(const bf16x8*)(kgb + 8);
  va = *(const bf16x8*)(vgb);
  vb = *(const bf16x8*)(vgb + 8);
  kgb += (size_t)64*NE; vgb += 64;
  __syncthreads();

#define MAKE_PU(PU, S0, S1, KS)                                                \
  { float e0,e1,e2,e3,e4,e5,e6,e7;                                             \
    if ((KS)==0)      { e0=S0[0]; e1=S0[1]; e2=S0[2]; e3=S0[3];                \
                        e4=S0[4]; e5=S0[5]; e6=S0[6]; e7=S0[7]; }              \
    else if ((KS)==1) { e0=S0[8]; e1=S0[9]; e2=S0[10];e3=S0[11];               \
                        e4=S0[12];e5=S0[13];e6=S0[14];e7=S0[15]; }             \
    else if ((KS)==2) { e0=S1[0]; e1=S1[1]; e2=S1[2]; e3=S1[3];                \
                        e4=S1[4]; e5=S1[5]; e6=S1[6]; e7=S1[7]; }              \
    else              { e0=S1[8]; e1=S1[9]; e2=S1[10];e3=S1[11];               \
                        e4=S1[12];e5=S1[13];e6=S1[14];e7=S1[15]; }             \
    unsigned a0,a1,b0,b1;                                                      \
    asm("v_cvt_pk_bf16_f32 %0, %1, %2" : "=v"(a0) : "v"(e0), "v"(e1));         \
    asm("v_cvt_pk_bf16_f32 %0, %1, %2" : "=v"(a1) : "v"(e2), "v"(e3));         \
    asm("v_cvt_pk_bf16_f32 %0, %1, %2" : "=v"(b0) : "v"(e4), "v"(e5));         \
    asm("v_cvt_pk_bf16_f32 %0, %1, %2" : "=v"(b1) : "v"(e6), "v"(e7));         \
    asm("v_permlane32_swap_b32 %0, %1" : "+v"(a0), "+v"(b0));                  \
    asm("v_permlane32_swap_b32 %0, %1" : "+v"(a1), "+v"(b1));                  \
    PU.u[0]=a0; PU.u[1]=a1; PU.u[2]=b0; PU.u[3]=b1; }

#define ATTN_TILE(P, T)                                                        \
  {                                                                            \
    const int t_ = (T);                                                        \
    if (t_ < NT-1) {                                                           \
      *(bf16x8*)((char*)smem + ((P)^1)*KBUFB + wb0)         = ka;              \
      *(bf16x8*)((char*)smem + ((P)^1)*KBUFB + wb1)         = kb;              \
      *(bf16x8*)((char*)smem + VOFFB + ((P)^1)*KBUFB + wb0) = va;              \
      *(bf16x8*)((char*)smem + VOFFB + ((P)^1)*KBUFB + wb1) = vb;              \
      if (t_ < NT-2) {                                                         \
        ka = *(const bf16x8*)(kgb);                                            \
        kb = *(const bf16x8*)(kgb + 8);                                        \
        va = *(const bf16x8*)(vgb);                                            \
        vb = *(const bf16x8*)(vgb + 8);                                        \
        kgb += (size_t)64*NE; vgb += 64;                                       \
      }                                                                        \
    }                                                                          \
    f32x16 sA0 = zero16(), sA1 = zero16(), sB0 = zero16(), sB1 = zero16();     \
    __builtin_amdgcn_s_setprio(1);                                             \
    _Pragma("unroll")                                                          \
    for (int s=0;s<4;s++) {                                                    \
      bf16x8 kf0 = *(const bf16x8*)(kr0[s] + (P)*KBUFB);                       \
      bf16x8 kf1 = *(const bf16x8*)(kr1[s] + (P)*KBUFB);                       \
      sA0 = __builtin_amdgcn_mfma_f32_32x32x16_bf16(kf0, qfA[s], sA0, 0,0,0);  \
      sB0 = __builtin_amdgcn_mfma_f32_32x32x16_bf16(kf0, qfB[s], sB0, 0,0,0);  \
      sA1 = __builtin_amdgcn_mfma_f32_32x32x16_bf16(kf1, qfA[s], sA1, 0,0,0);  \
      sB1 = __builtin_amdgcn_mfma_f32_32x32x16_bf16(kf1, qfB[s], sB1, 0,0,0);  \
    }                                                                          \
    __builtin_amdgcn_s_setprio(0);                                             \
    _Pragma("unroll")                                                          \
    for (int r=0;r<16;r++) { sA0[r] = __builtin_amdgcn_exp2f(sA0[r]); lpA += sA0[r]; } \
    _Pragma("unroll")                                                          \
    for (int r=0;r<16;r++) { sA1[r] = __builtin_amdgcn_exp2f(sA1[r]); lpA += sA1[r]; } \
    _Pragma("unroll")                                                          \
    for (int r=0;r<16;r++) { sB0[r] = __builtin_amdgcn_exp2f(sB0[r]); lpB += sB0[r]; } \
    _Pragma("unroll")                                                          \
    for (int r=0;r<16;r++) { sB1[r] = __builtin_amdgcn_exp2f(sB1[r]); lpB += sB1[r]; } \
    __builtin_amdgcn_s_setprio(1);                                             \
    _Pragma("unroll")                                                          \
    for (int ks=0;ks<4;ks++) {                                                 \
      union { unsigned u[4]; bf16x8 v; } puA, puB;                             \
      MAKE_PU(puA, sA0, sA1, ks);                                              \
      MAKE_PU(puB, sB0, sB1, ks);                                              \
      bf16x8 vf0, vf1;                                                         \
      if (ks==0) { vf0 = *(const bf16x8*)(kr0[0] + VOFFB + (P)*KBUFB);         \
                   vf1 = *(const bf16x8*)(kr1[0] + VOFFB + (P)*KBUFB); }       \
      else if (ks==1) { vf0 = *(const bf16x8*)(kr0[1] + VOFFB + (P)*KBUFB);    \
                   vf1 = *(const bf16x8*)(kr1[1] + VOFFB + (P)*KBUFB); }       \
      else if (ks==2) { vf0 = *(const bf16x8*)(kr0[2] + VOFFB + (P)*KBUFB);    \
                   vf1 = *(const bf16x8*)(kr1[2] + VOFFB + (P)*KBUFB); }       \
      else { vf0 = *(const bf16x8*)(kr0[3] + VOFFB + (P)*KBUFB);               \
             vf1 = *(const bf16x8*)(kr1[3] + VOFFB + (P)*KBUFB); }             \
      oA0 = __builtin_amdgcn_mfma_f32_32x32x16_bf16(puA.v, vf0, oA0, 0,0,0);   \
      oA1 = __builtin_amdgcn_mfma_f32_32x32x16_bf16(puA.v, vf1, oA1, 0,0,0);   \
      oB0 = __builtin_amdgcn_mfma_f32_32x32x16_bf16(puB.v, vf0, oB0, 0,0,0);   \
      oB1 = __builtin_amdgcn_mfma_f32_32x32x16_bf16(puB.v, vf1, oB1, 0,0,0);   \
    }                                                                          \
    __builtin_amdgcn_s_setprio(0);                                             \
    __syncthreads();                                                           \
  }

  for (int t2=0; t2<NT/2; ++t2) {
    ATTN_TILE(0, 2*t2);
    ATTN_TILE(1, 2*t2+1);
  }
#undef ATTN_TILE
#undef MAKE_PU

  // combine hi-halves of the rowsum, then one reciprocal per q-half per lane
  lpA += __shfl_xor(lpA, 32);
  lpB += __shfl_xor(lpB, 32);
  const float qs = q_scale[h];
  const float ivA_lane = qs / lpA;   // valid for q = lane&31
  const float ivB_lane = qs / lpB;
#pragma unroll
  for (int r=0;r<16;r++) {
    const int qi = (r&3) + 8*(r>>2) + hi*4;
    {
      const float iv = __shfl(ivA_lane, qi);
      bf16* op = aout + (size_t)(b*SEQ + q0 + qi)*DM + h*64 + l31;
      op[0]  = (bf16)(oA0[r]*iv);
      op[32] = (bf16)(oA1[r]*iv);
    }
    {
      const float iv = __shfl(ivB_lane, qi);
      bf16* op = aout + (size_t)(b*SEQ + q0 + 32 + qi)*DM + h*64 + l31;
      op[0]  = (bf16)(oB0[r]*iv);
      op[32] = (bf16)(oB1[r]*iv);
    }
  }
}

// ---------------- launch ----------------
extern "C" void kernel_launch(void* const* d_in, const int* in_sizes, int n_in,
                              void* d_out, int out_size, void* d_ws, size_t ws_size,
                              hipStream_t stream) {
  (void)in_sizes; (void)n_in; (void)out_size; (void)ws_size;
  const float* x  = (const float*)d_in[0];
  const float* wq = (const float*)d_in[1];
  const float* bq = (const float*)d_in[2];
  const float* wk = (const float*)d_in[3];
  const float* bk = (const float*)d_in[4];
  const float* wv = (const float*)d_in[5];
  const float* bv = (const float*)d_in[6];
  const float* wo = (const float*)d_in[7];
  const float* bo = (const float*)d_in[8];
  const float* temp = (const float*)d_in[9];
  const float* qsc  = (const float*)d_in[10];

  char* ws = (char*)d_ws;
  bf16* xb    = (bf16*)ws; ws += (size_t)MTOK*DM*2;
  bf16* wqkvb = (bf16*)ws; ws += (size_t)NE*DM*2;
  bf16* wob   = (bf16*)ws; ws += (size_t)DM*DM*2;
  float* bqkv = (float*)ws; ws += (size_t)NE*4;
  bf16* qkv   = (bf16*)ws; ws += (size_t)MTOK*NE*2;
  bf16* vt    = (bf16*)ws; ws += (size_t)NB*NHEADS*DHEAD*SEQ*2;
  bf16* aout  = (bf16*)ws; ws += (size_t)MTOK*DM*2;

  convert_kernel<<<dim3(1024), dim3(256), 0, stream>>>(x, wq, wk, wv, wo, bq, bk, bv,
                                                       xb, wqkvb, wob, bqkv);
  gemm_deep<0><<<dim3(MTOK/128, NE/128), dim3(256), 0, stream>>>(xb, wqkvb, bqkv, qkv,
                                                                 MTOK, NE, DM);
  transpose_v<<<dim3(SEQ/64, NB*NHEADS), dim3(256), 0, stream>>>(qkv, vt);
  attn_kernel<<<dim3(SEQ/256, NB*NHEADS), dim3(256), 0, stream>>>(qkv, vt, aout, temp, qsc);
  gemm_deep<1><<<dim3(MTOK/128, DM/128), dim3(256), 0, stream>>>(aout, wob, bo, d_out,
                                                                 MTOK, DM, DM);
}